// Round 4
// baseline (36.254 us; speedup 1.0000x reference)
//
#include <hip/hip_runtime.h>

// Depth-4 path signature, N=64, L=512, C=8. Output/batch:
// [sig1(8) | sig2(64) | sig3(512) | sig4(4096)] = 4680 f32.
//
// K1 sig_chunk2 (unchanged from R3): 16 chunks of ~32 segments scanned
//   independently, no LDS, wave-uniform float4 global loads, 2 triples/thread.
// K2 sig_fold_lds (NEW): per batch, fold 15 chunk sigs left-to-right (Chen):
//   n4 = A4+B4+A3*B1[l]+A2*B2[kl]+A1*B3[jkl]; n3 = A3+B3+A2*B1[k]+A1*B2[jk]
//   n2 = A2+B2+A1*B1[j]; n1 = A1+B1
//   R3's fold was latency-bound: 15 serial folds x ~11 scattered L3-latency
//   loads at 1 wave/SIMD. Fix: stage levels 1-3 of all 15 chunks into LDS
//   once (coalesced), level-3 l-major with 65-float stride (2-way banks);
//   per-fold reads become ds_reads. Only level-4 f-vectors stay global
//   (contiguous/coalesced), prefetched depth-3 in named register sets.

static constexpr int L = 512;
static constexpr int NC = 8;
static constexpr int NSEG = L - 1;               // 511
static constexpr int SIG = 8 + 64 + 512 + 4096;  // 4680
static constexpr int NB = 64;

__device__ __forceinline__ float sel8(float d0, float d1, float d2, float d3,
                                      float d4, float d5, float d6, float d7,
                                      bool b0, bool b1, bool b2) {
    float x0 = b0 ? d1 : d0;
    float x1 = b0 ? d3 : d2;
    float x2 = b0 ? d5 : d4;
    float x3 = b0 ? d7 : d6;
    float y0 = b1 ? x1 : x0;
    float y1 = b1 ? x3 : x2;
    return b2 ? y1 : y0;
}

template <int CH>
__global__ __launch_bounds__(256) void sig_chunk2(const float* __restrict__ path,
                                                  float* __restrict__ ws) {
    constexpr int SEGP = (NSEG + CH - 1) / CH;
    const int t = threadIdx.x;
    const int c = blockIdx.x % CH;
    const int n = blockIdx.x / CH;
    const int seg0 = c * SEGP;
    const int len = min(SEGP, NSEG - seg0);
    const float* p = path + (size_t)n * (L * NC) + (size_t)seg0 * NC;

    const bool i0 = t & 32, i1 = t & 64, i2 = t & 128;
    const bool j0 = t & 4, j1 = t & 8, j2 = t & 16;
    const bool kb0 = t & 1, kb1 = t & 2;

    float s1 = 0.f, s2 = 0.f, s3a = 0.f, s3b = 0.f;
    float4 va0 = {0, 0, 0, 0}, va1 = {0, 0, 0, 0};
    float4 vb0 = {0, 0, 0, 0}, vb1 = {0, 0, 0, 0};
    constexpr float c3 = 1.f / 6.f;
    constexpr float c4 = 1.f / 24.f;

    float4 p0 = *reinterpret_cast<const float4*>(p);
    float4 p1 = *reinterpret_cast<const float4*>(p + 4);
#pragma unroll 4
    for (int s = 0; s < len; ++s) {
        const float4 q0 = *reinterpret_cast<const float4*>(p + (s + 1) * 8);
        const float4 q1 = *reinterpret_cast<const float4*>(p + (s + 1) * 8 + 4);
        const float d0 = q0.x - p0.x, d1 = q0.y - p0.y;
        const float d2 = q0.z - p0.z, d3 = q0.w - p0.w;
        const float d4 = q1.x - p1.x, d5 = q1.y - p1.y;
        const float d6 = q1.z - p1.z, d7 = q1.w - p1.w;
        p0 = q0;
        p1 = q1;

        const float di = sel8(d0, d1, d2, d3, d4, d5, d6, d7, i0, i1, i2);
        const float dj = sel8(d0, d1, d2, d3, d4, d5, d6, d7, j0, j1, j2);
        const float xa = kb0 ? d2 : d0, xb = kb0 ? d6 : d4;
        const float dk0 = kb1 ? xb : xa;
        const float ya = kb0 ? d3 : d1, yb = kb0 ? d7 : d5;
        const float dk1 = kb1 ? yb : ya;

        const float u = fmaf(s1, c3, di * c4);
        float vv = fmaf(s1, dj * 0.5f, s2);
        vv = fmaf(di * dj, c3, vv);

        float Cc0 = fmaf(s2, dk0 * 0.5f, s3a);
        Cc0 = fmaf(dj * dk0, u, Cc0);
        float Cc1 = fmaf(s2, dk1 * 0.5f, s3b);
        Cc1 = fmaf(dj * dk1, u, Cc1);

        va0.x = fmaf(d0, Cc0, va0.x);
        va0.y = fmaf(d1, Cc0, va0.y);
        va0.z = fmaf(d2, Cc0, va0.z);
        va0.w = fmaf(d3, Cc0, va0.w);
        va1.x = fmaf(d4, Cc0, va1.x);
        va1.y = fmaf(d5, Cc0, va1.y);
        va1.z = fmaf(d6, Cc0, va1.z);
        va1.w = fmaf(d7, Cc0, va1.w);
        vb0.x = fmaf(d0, Cc1, vb0.x);
        vb0.y = fmaf(d1, Cc1, vb0.y);
        vb0.z = fmaf(d2, Cc1, vb0.z);
        vb0.w = fmaf(d3, Cc1, vb0.w);
        vb1.x = fmaf(d4, Cc1, vb1.x);
        vb1.y = fmaf(d5, Cc1, vb1.y);
        vb1.z = fmaf(d6, Cc1, vb1.z);
        vb1.w = fmaf(d7, Cc1, vb1.w);

        s3a = fmaf(dk0, vv, s3a);
        s3b = fmaf(dk1, vv, s3b);
        s2 = fmaf(dj, fmaf(di, 0.5f, s1), s2);
        s1 += di;
    }

    float* o = ws + ((size_t)n * CH + c) * SIG;
    float* o4 = o + 584 + t * 16;
    *reinterpret_cast<float4*>(o4) = va0;
    *reinterpret_cast<float4*>(o4 + 4) = va1;
    *reinterpret_cast<float4*>(o4 + 8) = vb0;
    *reinterpret_cast<float4*>(o4 + 12) = vb1;
    o[72 + 2 * t] = s3a;
    o[72 + 2 * t + 1] = s3b;
    if ((t & 3) == 0) {
        o[8 + (t >> 2)] = s2;
        if ((t & 31) == 0) o[t >> 5] = s1;
    }
}

// Fold with LDS-staged B-side levels 1-3. CH must be 16.
__global__ __launch_bounds__(128) void sig_fold_lds(const float* __restrict__ ws,
                                                    float* __restrict__ out) {
    constexpr int CH = 16;
    constexpr int CS = 592;  // per-chunk LDS floats: 72 flat + 8*65 l-major L3
    __shared__ float lds[(CH - 1) * CS];  // 35520 B

    const int t = threadIdx.x;
    const int q = blockIdx.x & 3;
    const int n = blockIdx.x >> 2;
    const float* Bs = ws + (size_t)n * CH * SIG;

    // Stage chunks 1..15, floats 0..583 (levels 1-3), coalesced float4 reads.
    // float4 index s: 0..17 -> flat copy; 18..145 -> level-3 l-major scatter.
#pragma unroll
    for (int r = 0; r < 18; ++r) {
        const int u = r * 128 + t;
        if (u < (CH - 1) * 146) {
            const int c = u / 146;           // chunk-1 (0..14)
            const int s = u - c * 146;       // float4 index within 584
            const float4 v =
                *reinterpret_cast<const float4*>(Bs + (size_t)(c + 1) * SIG + s * 4);
            float* base = lds + c * CS;
            if (s < 18) {
                *reinterpret_cast<float4*>(base + s * 4) = v;
            } else {
                const int q4 = s - 18;               // 0..127
                const int j3 = q4 >> 4;              // j
                const int k3 = (q4 >> 1) & 7;        // k
                const int l4 = (q4 & 1) * 4;         // l base
                float* d3 = base + 72 + j3 * 8 + k3;
                d3[(l4 + 0) * 65] = v.x;
                d3[(l4 + 1) * 65] = v.y;
                d3[(l4 + 2) * 65] = v.z;
                d3[(l4 + 3) * 65] = v.w;
            }
        }
    }

    const int tri = q * 128 + t;
    const int i = tri >> 6;          // wave-uniform
    const int j = (tri >> 3) & 7;
    const int k = tri & 7;

    // Prefix init from chunk 0 (global, one-time) + first 3 f-sets in flight.
    float a1 = Bs[i];
    float a2 = Bs[8 + (tri >> 3)];
    float a3 = Bs[72 + tri];
    float4 a40 = *reinterpret_cast<const float4*>(Bs + 584 + tri * 8);
    float4 a41 = *reinterpret_cast<const float4*>(Bs + 584 + tri * 8 + 4);

    float4 Af0, Af1, Bf0, Bf1, Cf0, Cf1;
#define LOADF(P, c)                                                            \
    {                                                                          \
        const float* fp = Bs + (size_t)(c)*SIG + 584 + tri * 8;                \
        P##f0 = *reinterpret_cast<const float4*>(fp);                          \
        P##f1 = *reinterpret_cast<const float4*>(fp + 4);                      \
    }
    LOADF(A, 1)
    LOADF(B, 2)
    LOADF(C, 3)

    __syncthreads();

#define FOLDC(P, c)                                                                   \
    {                                                                                 \
        const float* base = lds + (c - 1) * CS;                                       \
        const float4 l0 = *reinterpret_cast<const float4*>(base);                     \
        const float4 l1 = *reinterpret_cast<const float4*>(base + 4);                 \
        const float4 k0 = *reinterpret_cast<const float4*>(base + 8 + k * 8);         \
        const float4 k1 = *reinterpret_cast<const float4*>(base + 8 + k * 8 + 4);     \
        const float b1i = base[i], b1j = base[j], b1k = base[k];                      \
        const float b2ij = base[8 + i * 8 + j], b2jk = base[8 + j * 8 + k];           \
        const float b3 = base[72 + k * 65 + i * 8 + j];                               \
        const float* mp = base + 72 + j * 8 + k;                                      \
        const float m_0 = mp[0 * 65], m_1 = mp[1 * 65], m_2 = mp[2 * 65];             \
        const float m_3 = mp[3 * 65], m_4 = mp[4 * 65], m_5 = mp[5 * 65];             \
        const float m_6 = mp[6 * 65], m_7 = mp[7 * 65];                               \
        a40.x = fmaf(a3, l0.x, fmaf(a2, k0.x, fmaf(a1, m_0, a40.x + P##f0.x)));       \
        a40.y = fmaf(a3, l0.y, fmaf(a2, k0.y, fmaf(a1, m_1, a40.y + P##f0.y)));       \
        a40.z = fmaf(a3, l0.z, fmaf(a2, k0.z, fmaf(a1, m_2, a40.z + P##f0.z)));       \
        a40.w = fmaf(a3, l0.w, fmaf(a2, k0.w, fmaf(a1, m_3, a40.w + P##f0.w)));       \
        a41.x = fmaf(a3, l1.x, fmaf(a2, k1.x, fmaf(a1, m_4, a41.x + P##f1.x)));       \
        a41.y = fmaf(a3, l1.y, fmaf(a2, k1.y, fmaf(a1, m_5, a41.y + P##f1.y)));       \
        a41.z = fmaf(a3, l1.z, fmaf(a2, k1.z, fmaf(a1, m_6, a41.z + P##f1.z)));       \
        a41.w = fmaf(a3, l1.w, fmaf(a2, k1.w, fmaf(a1, m_7, a41.w + P##f1.w)));       \
        a3 = fmaf(a2, b1k, fmaf(a1, b2jk, a3 + b3));                                  \
        a2 = fmaf(a1, b1j, a2 + b2ij);                                                \
        a1 += b1i;                                                                    \
    }

    FOLDC(A, 1)  LOADF(A, 4)
    FOLDC(B, 2)  LOADF(B, 5)
    FOLDC(C, 3)  LOADF(C, 6)
    FOLDC(A, 4)  LOADF(A, 7)
    FOLDC(B, 5)  LOADF(B, 8)
    FOLDC(C, 6)  LOADF(C, 9)
    FOLDC(A, 7)  LOADF(A, 10)
    FOLDC(B, 8)  LOADF(B, 11)
    FOLDC(C, 9)  LOADF(C, 12)
    FOLDC(A, 10) LOADF(A, 13)
    FOLDC(B, 11) LOADF(B, 14)
    FOLDC(C, 12) LOADF(C, 15)
    FOLDC(A, 13)
    FOLDC(B, 14)
    FOLDC(C, 15)
#undef LOADF
#undef FOLDC

    float* o = out + (size_t)n * SIG;
    *reinterpret_cast<float4*>(o + 584 + tri * 8) = a40;
    *reinterpret_cast<float4*>(o + 584 + tri * 8 + 4) = a41;
    o[72 + tri] = a3;
    if (k == 0) {
        o[8 + (tri >> 3)] = a2;
        if (j == 0) o[i] = a1;
    }
}

// --- fallback (round-1 kernel) if workspace is too small -------------------
__global__ __launch_bounds__(256) void sig_kernel(const float* __restrict__ path,
                                                  float* __restrict__ out) {
    __shared__ float dx[NSEG * NC];
    const int t = threadIdx.x;
    const int blk = blockIdx.x;
    const int n = blk >> 2;
    const int part = blk & 3;
    const float* p = path + (size_t)n * (L * NC);
    for (int e = t; e < NSEG * NC; e += 256)
        dx[e] = p[e + NC] - p[e];
    __syncthreads();

    const int idx = part * 256 + t;
    const int tri = idx >> 1;
    const int lh = (idx & 1) << 2;
    const int i = tri >> 6;
    const int j = (tri >> 3) & 7;
    const int k = tri & 7;

    float s1 = 0.f, s2 = 0.f, s3 = 0.f;
    float s40 = 0.f, s41 = 0.f, s42 = 0.f, s43 = 0.f;
    constexpr float c3 = 1.f / 6.f;
    constexpr float c4 = 1.f / 24.f;

    const float* d = dx;
#pragma unroll 2
    for (int s = 0; s < NSEG; ++s, d += NC) {
        const float di = d[i];
        const float dj = d[j];
        const float dk = d[k];
        const float4 dl = *reinterpret_cast<const float4*>(d + lh);
        const float djk = dj * dk;
        const float u = fmaf(s1, c3, di * c4);
        float Cc = fmaf(s2, dk * 0.5f, s3);
        Cc = fmaf(djk, u, Cc);
        s40 = fmaf(dl.x, Cc, s40);
        s41 = fmaf(dl.y, Cc, s41);
        s42 = fmaf(dl.z, Cc, s42);
        s43 = fmaf(dl.w, Cc, s43);
        float v = fmaf(s1, dj * 0.5f, s2);
        v = fmaf(di * dj, c3, v);
        s3 = fmaf(dk, v, s3);
        s2 = fmaf(dj, fmaf(di, 0.5f, s1), s2);
        s1 += di;
    }

    float* o = out + (size_t)n * SIG;
    float4 r;
    r.x = s40; r.y = s41; r.z = s42; r.w = s43;
    *reinterpret_cast<float4*>(o + 584 + tri * 8 + lh) = r;
    if (lh == 0) {
        o[72 + tri] = s3;
        if (k == 0) {
            o[8 + (tri >> 3)] = s2;
            if (j == 0) o[i] = s1;
        }
    }
}

extern "C" void kernel_launch(void* const* d_in, const int* in_sizes, int n_in,
                              void* d_out, int out_size, void* d_ws, size_t ws_size,
                              hipStream_t stream) {
    const float* path = (const float*)d_in[0];
    float* out = (float*)d_out;
    float* ws = (float*)d_ws;

    const size_t need16 = (size_t)NB * 16 * SIG * sizeof(float);  // ~19.2 MB

    if (ws_size >= need16) {
        sig_chunk2<16><<<NB * 16, 256, 0, stream>>>(path, ws);
        sig_fold_lds<<<NB * 4, 128, 0, stream>>>(ws, out);
    } else {
        sig_kernel<<<256, 256, 0, stream>>>(path, out);
    }
}

// Round 5
// 35.723 us; speedup vs baseline: 1.0149x; 1.0149x over previous
//
#include <hip/hip_runtime.h>

// Depth-4 path signature, N=64, L=512, C=8. Output/batch:
// [sig1(8) | sig2(64) | sig3(512) | sig4(4096)] = 4680 f32.
//
// K1 sig_chunk3: 16 chunks of ~32 segments scanned independently.
//   Thread owns a full k-row: (i,j) fixed, k=0..7, all 8 l's => 64 acc.
//   Cc_k = s3[k] + dk*(s2/2 + dj*u)  -> 1 FMA per k for the coefficient.
//   128-thr blocks (2 chunks), grid 64*8; __launch_bounds__(128,4) caps
//   VGPR at 128 (R4 theory: unbounded VGPR -> occupancy collapse/spill).
// K2 sig_fold_lds: per batch fold 15 chunk sigs left-to-right (Chen):
//   n4 = A4+B4+A3*B1[l]+A2*B2[kl]+A1*B3[jkl]; n3 = A3+B3+A2*B1[k]+A1*B2[jk]
//   n2 = A2+B2+A1*B1[j]; n1 = A1+B1
//   Levels 1-3 of all 15 chunks staged in LDS (l-major level-3, stride 65);
//   level-4 f-vectors stay global (coalesced), depth-3 register prefetch.

static constexpr int L = 512;
static constexpr int NC = 8;
static constexpr int NSEG = L - 1;               // 511
static constexpr int SIG = 8 + 64 + 512 + 4096;  // 4680
static constexpr int NB = 64;

__device__ __forceinline__ float sel8(float d0, float d1, float d2, float d3,
                                      float d4, float d5, float d6, float d7,
                                      bool b0, bool b1, bool b2) {
    float x0 = b0 ? d1 : d0;
    float x1 = b0 ? d3 : d2;
    float x2 = b0 ? d5 : d4;
    float x3 = b0 ? d7 : d6;
    float y0 = b1 ? x1 : x0;
    float y1 = b1 ? x3 : x2;
    return b2 ? y1 : y0;
}

template <int CH>
__global__ __launch_bounds__(128, 4) void sig_chunk3(const float* __restrict__ path,
                                                     float* __restrict__ ws) {
    constexpr int SEGP = (NSEG + CH - 1) / CH;  // 32
    const int t = threadIdx.x;      // 0..127
    const int csub = t >> 6;        // 0/1
    const int ij = t & 63;          // (i,j)
    const int n = blockIdx.x >> 3;
    const int c = ((blockIdx.x & 7) << 1) | csub;
    const int seg0 = c * SEGP;
    const int len = min(SEGP, NSEG - seg0);
    const float* p = path + (size_t)n * (L * NC) + (size_t)seg0 * NC;

    const bool ib0 = ij & 8, ib1 = ij & 16, ib2 = ij & 32;
    const bool jb0 = ij & 1, jb1 = ij & 2, jb2 = ij & 4;

    float s1 = 0.f, s2 = 0.f;
    float s3[8];
    float4 a0[8], a1[8];
#pragma unroll
    for (int k = 0; k < 8; ++k) {
        s3[k] = 0.f;
        a0[k] = make_float4(0.f, 0.f, 0.f, 0.f);
        a1[k] = make_float4(0.f, 0.f, 0.f, 0.f);
    }
    constexpr float c3 = 1.f / 6.f;
    constexpr float c4 = 1.f / 24.f;

    float4 p0 = *reinterpret_cast<const float4*>(p);
    float4 p1 = *reinterpret_cast<const float4*>(p + 4);
#pragma unroll 2
    for (int s = 0; s < len; ++s) {
        const float4 q0 = *reinterpret_cast<const float4*>(p + (s + 1) * 8);
        const float4 q1 = *reinterpret_cast<const float4*>(p + (s + 1) * 8 + 4);
        float dd[8];
        dd[0] = q0.x - p0.x; dd[1] = q0.y - p0.y;
        dd[2] = q0.z - p0.z; dd[3] = q0.w - p0.w;
        dd[4] = q1.x - p1.x; dd[5] = q1.y - p1.y;
        dd[6] = q1.z - p1.z; dd[7] = q1.w - p1.w;
        p0 = q0;
        p1 = q1;

        const float di = sel8(dd[0], dd[1], dd[2], dd[3], dd[4], dd[5], dd[6], dd[7],
                              ib0, ib1, ib2);
        const float dj = sel8(dd[0], dd[1], dd[2], dd[3], dd[4], dd[5], dd[6], dd[7],
                              jb0, jb1, jb2);

        const float u = fmaf(s1, c3, di * c4);   // s1/6 + di/24
        float vv = fmaf(s1, dj * 0.5f, s2);      // s2 + s1*dj/2
        vv = fmaf(di * dj, c3, vv);              // + di*dj/6
        const float w = fmaf(s2, 0.5f, dj * u);  // s2/2 + dj*u

#pragma unroll
        for (int k = 0; k < 8; ++k) {
            const float dk = dd[k];
            const float Cc = fmaf(dk, w, s3[k]);
            a0[k].x = fmaf(dd[0], Cc, a0[k].x);
            a0[k].y = fmaf(dd[1], Cc, a0[k].y);
            a0[k].z = fmaf(dd[2], Cc, a0[k].z);
            a0[k].w = fmaf(dd[3], Cc, a0[k].w);
            a1[k].x = fmaf(dd[4], Cc, a1[k].x);
            a1[k].y = fmaf(dd[5], Cc, a1[k].y);
            a1[k].z = fmaf(dd[6], Cc, a1[k].z);
            a1[k].w = fmaf(dd[7], Cc, a1[k].w);
            s3[k] = fmaf(dk, vv, s3[k]);
        }
        s2 = fmaf(dj, fmaf(di, 0.5f, s1), s2);
        s1 += di;
    }

    float* o = ws + ((size_t)n * CH + c) * SIG;
    float* o4 = o + 584 + ij * 64;
#pragma unroll
    for (int k = 0; k < 8; ++k) {
        *reinterpret_cast<float4*>(o4 + k * 8) = a0[k];
        *reinterpret_cast<float4*>(o4 + k * 8 + 4) = a1[k];
    }
    float4 s3v0 = make_float4(s3[0], s3[1], s3[2], s3[3]);
    float4 s3v1 = make_float4(s3[4], s3[5], s3[6], s3[7]);
    *reinterpret_cast<float4*>(o + 72 + ij * 8) = s3v0;
    *reinterpret_cast<float4*>(o + 72 + ij * 8 + 4) = s3v1;
    o[8 + ij] = s2;
    if ((ij & 7) == 0) o[ij >> 3] = s1;
}

// Fold with LDS-staged B-side levels 1-3. CH must be 16.
__global__ __launch_bounds__(256, 4) void sig_fold_lds(const float* __restrict__ ws,
                                                       float* __restrict__ out) {
    constexpr int CH = 16;
    constexpr int CS = 592;  // per-chunk LDS floats: 72 flat + 8*65 l-major L3
    __shared__ float lds[(CH - 1) * CS];  // 35520 B

    const int t = threadIdx.x;           // 0..255
    const int q = blockIdx.x & 1;
    const int n = blockIdx.x >> 1;
    const float* Bs = ws + (size_t)n * CH * SIG;

    // Stage chunks 1..15, floats 0..583 (levels 1-3): (CH-1)*146=2190 float4.
#pragma unroll
    for (int r = 0; r < 9; ++r) {
        const int u = r * 256 + t;
        if (u < (CH - 1) * 146) {
            const int c = u / 146;
            const int s = u - c * 146;
            const float4 v =
                *reinterpret_cast<const float4*>(Bs + (size_t)(c + 1) * SIG + s * 4);
            float* base = lds + c * CS;
            if (s < 18) {
                *reinterpret_cast<float4*>(base + s * 4) = v;
            } else {
                const int q4 = s - 18;               // 0..127
                const int j3 = q4 >> 4;
                const int k3 = (q4 >> 1) & 7;
                const int l4 = (q4 & 1) * 4;
                float* d3 = base + 72 + j3 * 8 + k3;
                d3[(l4 + 0) * 65] = v.x;
                d3[(l4 + 1) * 65] = v.y;
                d3[(l4 + 2) * 65] = v.z;
                d3[(l4 + 3) * 65] = v.w;
            }
        }
    }

    const int tri = q * 256 + t;
    const int i = tri >> 6;
    const int j = (tri >> 3) & 7;
    const int k = tri & 7;

    float a1 = Bs[i];
    float a2 = Bs[8 + (tri >> 3)];
    float a3 = Bs[72 + tri];
    float4 a40 = *reinterpret_cast<const float4*>(Bs + 584 + tri * 8);
    float4 a41 = *reinterpret_cast<const float4*>(Bs + 584 + tri * 8 + 4);

    float4 Af0, Af1, Bf0, Bf1, Cf0, Cf1;
#define LOADF(P, c)                                                            \
    {                                                                          \
        const float* fp = Bs + (size_t)(c)*SIG + 584 + tri * 8;                \
        P##f0 = *reinterpret_cast<const float4*>(fp);                          \
        P##f1 = *reinterpret_cast<const float4*>(fp + 4);                      \
    }
    LOADF(A, 1)
    LOADF(B, 2)
    LOADF(C, 3)

    __syncthreads();

#define FOLDC(P, c)                                                                   \
    {                                                                                 \
        const float* base = lds + (c - 1) * CS;                                       \
        const float4 l0 = *reinterpret_cast<const float4*>(base);                     \
        const float4 l1 = *reinterpret_cast<const float4*>(base + 4);                 \
        const float4 k0 = *reinterpret_cast<const float4*>(base + 8 + k * 8);         \
        const float4 k1 = *reinterpret_cast<const float4*>(base + 8 + k * 8 + 4);     \
        const float b1i = base[i], b1j = base[j], b1k = base[k];                      \
        const float b2ij = base[8 + i * 8 + j], b2jk = base[8 + j * 8 + k];           \
        const float b3 = base[72 + k * 65 + i * 8 + j];                               \
        const float* mp = base + 72 + j * 8 + k;                                      \
        const float m_0 = mp[0 * 65], m_1 = mp[1 * 65], m_2 = mp[2 * 65];             \
        const float m_3 = mp[3 * 65], m_4 = mp[4 * 65], m_5 = mp[5 * 65];             \
        const float m_6 = mp[6 * 65], m_7 = mp[7 * 65];                               \
        a40.x = fmaf(a3, l0.x, fmaf(a2, k0.x, fmaf(a1, m_0, a40.x + P##f0.x)));       \
        a40.y = fmaf(a3, l0.y, fmaf(a2, k0.y, fmaf(a1, m_1, a40.y + P##f0.y)));       \
        a40.z = fmaf(a3, l0.z, fmaf(a2, k0.z, fmaf(a1, m_2, a40.z + P##f0.z)));       \
        a40.w = fmaf(a3, l0.w, fmaf(a2, k0.w, fmaf(a1, m_3, a40.w + P##f0.w)));       \
        a41.x = fmaf(a3, l1.x, fmaf(a2, k1.x, fmaf(a1, m_4, a41.x + P##f1.x)));       \
        a41.y = fmaf(a3, l1.y, fmaf(a2, k1.y, fmaf(a1, m_5, a41.y + P##f1.y)));       \
        a41.z = fmaf(a3, l1.z, fmaf(a2, k1.z, fmaf(a1, m_6, a41.z + P##f1.z)));       \
        a41.w = fmaf(a3, l1.w, fmaf(a2, k1.w, fmaf(a1, m_7, a41.w + P##f1.w)));       \
        a3 = fmaf(a2, b1k, fmaf(a1, b2jk, a3 + b3));                                  \
        a2 = fmaf(a1, b1j, a2 + b2ij);                                                \
        a1 += b1i;                                                                    \
    }

    FOLDC(A, 1)  LOADF(A, 4)
    FOLDC(B, 2)  LOADF(B, 5)
    FOLDC(C, 3)  LOADF(C, 6)
    FOLDC(A, 4)  LOADF(A, 7)
    FOLDC(B, 5)  LOADF(B, 8)
    FOLDC(C, 6)  LOADF(C, 9)
    FOLDC(A, 7)  LOADF(A, 10)
    FOLDC(B, 8)  LOADF(B, 11)
    FOLDC(C, 9)  LOADF(C, 12)
    FOLDC(A, 10) LOADF(A, 13)
    FOLDC(B, 11) LOADF(B, 14)
    FOLDC(C, 12) LOADF(C, 15)
    FOLDC(A, 13)
    FOLDC(B, 14)
    FOLDC(C, 15)
#undef LOADF
#undef FOLDC

    float* o = out + (size_t)n * SIG;
    *reinterpret_cast<float4*>(o + 584 + tri * 8) = a40;
    *reinterpret_cast<float4*>(o + 584 + tri * 8 + 4) = a41;
    o[72 + tri] = a3;
    if (k == 0) {
        o[8 + (tri >> 3)] = a2;
        if (j == 0) o[i] = a1;
    }
}

// --- fallback (round-1 kernel) if workspace is too small -------------------
__global__ __launch_bounds__(256) void sig_kernel(const float* __restrict__ path,
                                                  float* __restrict__ out) {
    __shared__ float dx[NSEG * NC];
    const int t = threadIdx.x;
    const int blk = blockIdx.x;
    const int n = blk >> 2;
    const int part = blk & 3;
    const float* p = path + (size_t)n * (L * NC);
    for (int e = t; e < NSEG * NC; e += 256)
        dx[e] = p[e + NC] - p[e];
    __syncthreads();

    const int idx = part * 256 + t;
    const int tri = idx >> 1;
    const int lh = (idx & 1) << 2;
    const int i = tri >> 6;
    const int j = (tri >> 3) & 7;
    const int k = tri & 7;

    float s1 = 0.f, s2 = 0.f, s3 = 0.f;
    float s40 = 0.f, s41 = 0.f, s42 = 0.f, s43 = 0.f;
    constexpr float c3 = 1.f / 6.f;
    constexpr float c4 = 1.f / 24.f;

    const float* d = dx;
#pragma unroll 2
    for (int s = 0; s < NSEG; ++s, d += NC) {
        const float di = d[i];
        const float dj = d[j];
        const float dk = d[k];
        const float4 dl = *reinterpret_cast<const float4*>(d + lh);
        const float djk = dj * dk;
        const float u = fmaf(s1, c3, di * c4);
        float Cc = fmaf(s2, dk * 0.5f, s3);
        Cc = fmaf(djk, u, Cc);
        s40 = fmaf(dl.x, Cc, s40);
        s41 = fmaf(dl.y, Cc, s41);
        s42 = fmaf(dl.z, Cc, s42);
        s43 = fmaf(dl.w, Cc, s43);
        float v = fmaf(s1, dj * 0.5f, s2);
        v = fmaf(di * dj, c3, v);
        s3 = fmaf(dk, v, s3);
        s2 = fmaf(dj, fmaf(di, 0.5f, s1), s2);
        s1 += di;
    }

    float* o = out + (size_t)n * SIG;
    float4 r;
    r.x = s40; r.y = s41; r.z = s42; r.w = s43;
    *reinterpret_cast<float4*>(o + 584 + tri * 8 + lh) = r;
    if (lh == 0) {
        o[72 + tri] = s3;
        if (k == 0) {
            o[8 + (tri >> 3)] = s2;
            if (j == 0) o[i] = s1;
        }
    }
}

extern "C" void kernel_launch(void* const* d_in, const int* in_sizes, int n_in,
                              void* d_out, int out_size, void* d_ws, size_t ws_size,
                              hipStream_t stream) {
    const float* path = (const float*)d_in[0];
    float* out = (float*)d_out;
    float* ws = (float*)d_ws;

    const size_t need16 = (size_t)NB * 16 * SIG * sizeof(float);  // ~19.2 MB

    if (ws_size >= need16) {
        sig_chunk3<16><<<NB * 8, 128, 0, stream>>>(path, ws);
        sig_fold_lds<<<NB * 2, 256, 0, stream>>>(ws, out);
    } else {
        sig_kernel<<<256, 256, 0, stream>>>(path, out);
    }
}